// Round 3
// baseline (370.304 us; speedup 1.0000x reference)
//
#include <hip/hip_runtime.h>
#include <hip/hip_bf16.h>

// Problem dims
#define B_    512
#define S_    50
#define D_    100
#define NS_   12
#define LAST_ 3
#define NADJ_ 12
#define SCALE_ 0.1f

// ---------------------------------------------------------------------------
// Fused local (star) + global (neighbor) branch + combine. One block per b.
// All tensors fp32 (reference dtype). No workspace usage.
//
// STEP==1 => the reference's beta/softmax/star-update after the gate combine
// is dead code (star is never read again). Gate trick: (h@Wq)·(star@Wk)
// = h·(Wq@(star@Wk)) — two matvecs instead of a [50,100]x[100,100] GEMM.
// ---------------------------------------------------------------------------
__global__ __launch_bounds__(256, 2) void fused_kernel(
    const int* __restrict__ inputs,       // [B,S]
    const float* __restrict__ adj,        // [B,S,S]
    const float* __restrict__ emb,        // [N,D]
    const int* __restrict__ adj_all,      // [N,NS]
    const float* __restrict__ num_w,      // [N,NS]
    const float* __restrict__ sW,         // [2]
    const float* __restrict__ Wa,         // [D,D]
    const float* __restrict__ Wq,         // [D,D]
    const float* __restrict__ Wk,         // [D,D]
    const float* __restrict__ Wg,         // [2D,D]
    float* __restrict__ out)              // [B,S,D]
{
    __shared__ __align__(16) float hL[S_][D_];    // 20000 B  original h
    __shared__ __align__(16) float adjL[S_][S_];  // 10000 B
    __shared__ __align__(16) float hwa[S_][D_];   // 20000 B  h@Wa, later aggL
    __shared__ float ssq[S_][25];                 //  5000 B
    __shared__ float star[D_], kb[D_], kq[D_];
    __shared__ float gate[S_], rinv[S_], rinv2[S_];
    __shared__ int   ids[S_];
    __shared__ int   nid[S_ * NS_];
    __shared__ float alf[S_ * NS_];
    __shared__ float denom;
    // total ~61.8 KB -> 2 blocks/CU

    const int b = blockIdx.x, t = threadIdx.x;
    const float s0 = sW[0], s1 = sW[1];

    if (t < S_) ids[t] = inputs[b * S_ + t];
    __syncthreads();

    // ---- gather h rows and adj tile into LDS (float4 loads) ----
    for (int e = t; e < S_ * D_ / 4; e += 256) {          // 1250 quads
        int s = e / 25, dq = e - s * 25;
        ((float4*)&hL[0][0])[e] = ((const float4*)(emb + ids[s] * D_))[dq];
    }
    for (int e = t; e < S_ * S_ / 4; e += 256) {          // 625 quads
        ((float4*)&adjL[0][0])[e] = ((const float4*)(adj + b * S_ * S_))[e];
    }
    __syncthreads();

    if (t == 0) {
        float c = 0.f;
        for (int s = 0; s < S_; ++s) c += (ids[s] != 0) ? 1.f : 0.f;
        denom = fmaxf(c, 1.f);
    }
    __syncthreads();

    // star = masked mean over s
    if (t < D_) {
        float a = 0.f;
        for (int s = 0; s < S_; ++s) if (ids[s] != 0) a += hL[s][t];
        star[t] = a / denom;
    }
    __syncthreads();

    // kb = star @ Wk  (column reads, coalesced across lanes per k)
    if (t < D_) {
        float a = 0.f;
        for (int k = 0; k < D_; ++k) a = fmaf(star[k], Wk[k * D_ + t], a);
        kb[t] = a;
    }
    __syncthreads();

    // kq[k] = Wq[k,:]·kb  (row-major dot per thread)
    if (t < D_) {
        float a = 0.f;
        const float4* wr = (const float4*)(Wq + t * D_);
#pragma unroll 5
        for (int j = 0; j < 25; ++j) {
            float4 u = wr[j]; int k = j * 4;
            a = fmaf(u.x, kb[k + 0], a);
            a = fmaf(u.y, kb[k + 1], a);
            a = fmaf(u.z, kb[k + 2], a);
            a = fmaf(u.w, kb[k + 3], a);
        }
        kq[t] = a;
    }
    __syncthreads();

    // gate[s] = sigmoid(SCALE * h[s]·kq)
    if (t < S_) {
        float a = 0.f;
        for (int k = 0; k < D_; ++k) a = fmaf(hL[t][k], kq[k], a);
        gate[t] = 1.f / (1.f + expf(-a * SCALE_));
    }
    // (gate readers sync at the barrier after the hwa GEMM)

    const bool act = (t < 250);
    int sg = 0, dg = 0, sb = 0, d4 = 0;
    if (act) { sg = t / 25; dg = t - sg * 25; sb = sg * 5; d4 = dg * 4; }

    // ---- hwa = h @ Wa : 5 rows x 4 cols per thread ----
    if (act) {
        float acc[5][4] = {};
        for (int k = 0; k < D_; ++k) {
            float4 w = ((const float4*)(Wa + k * D_))[dg];
#pragma unroll
            for (int i = 0; i < 5; ++i) {
                float xv = hL[sb + i][k];
                acc[i][0] = fmaf(xv, w.x, acc[i][0]);
                acc[i][1] = fmaf(xv, w.y, acc[i][1]);
                acc[i][2] = fmaf(xv, w.z, acc[i][2]);
                acc[i][3] = fmaf(xv, w.w, acc[i][3]);
            }
        }
#pragma unroll
        for (int i = 0; i < 5; ++i)
#pragma unroll
            for (int j = 0; j < 4; ++j) hwa[sb + i][d4 + j] = acc[i][j];
    }
    __syncthreads();

    // ---- h_n = adj @ hwa; hl = (1-g)*h_n + g*star  (kept in registers) ----
    float hl[5][4] = {};
    if (act) {
        for (int k = 0; k < S_; ++k) {
            float4 w = ((const float4*)&hwa[k][0])[dg];
#pragma unroll
            for (int i = 0; i < 5; ++i) {
                float av = adjL[sb + i][k];
                hl[i][0] = fmaf(av, w.x, hl[i][0]);
                hl[i][1] = fmaf(av, w.y, hl[i][1]);
                hl[i][2] = fmaf(av, w.z, hl[i][2]);
                hl[i][3] = fmaf(av, w.w, hl[i][3]);
            }
        }
#pragma unroll
        for (int i = 0; i < 5; ++i) {
            float g = gate[sb + i];
#pragma unroll
            for (int j = 0; j < 4; ++j)
                hl[i][j] = (1.f - g) * hl[i][j] + g * star[d4 + j];
            ssq[sb + i][dg] = hl[i][0]*hl[i][0] + hl[i][1]*hl[i][1]
                            + hl[i][2]*hl[i][2] + hl[i][3]*hl[i][3];
        }
    }
    __syncthreads();

    // row inv-norms (fold s0); concurrently load neighbor ids/weights
    if (t < S_) {
        float ss = 0.f;
        for (int j = 0; j < 25; ++j) ss += ssq[t][j];
        rinv[t] = s0 / fmaxf(sqrtf(ss), 1e-12f);
    }
    for (int e = t; e < S_ * NS_; e += 256) {             // 600
        int r = e / NS_, n = e - r * NS_;
        nid[e] = adj_all[ids[r] * NS_ + n];
        alf[e] = num_w[ids[r] * NS_ + n];
    }
    __syncthreads();

    // softmax(alpha) per row; normalize hl registers
    if (t < S_) {
        float mx = -1e30f;
        for (int n = 0; n < NS_; ++n) mx = fmaxf(mx, alf[t * NS_ + n]);
        float e[NS_]; float sm = 0.f;
        for (int n = 0; n < NS_; ++n) { e[n] = expf(alf[t * NS_ + n] - mx); sm += e[n]; }
        float inv = 1.f / sm;
        for (int n = 0; n < NS_; ++n) alf[t * NS_ + n] = e[n] * inv;
    }
    if (act) {
#pragma unroll
        for (int i = 0; i < 5; ++i) {
            float f = rinv[sb + i];
#pragma unroll
            for (int j = 0; j < 4; ++j) hl[i][j] *= f;
        }
    }
    __syncthreads();

    // ---- agg = softmax(num_w) · emb[neighbors]  -> reuse hwa as aggL ----
    if (act) {
#pragma unroll
        for (int i = 0; i < 5; ++i) {
            int row = sb + i;
            float a0 = 0.f, a1 = 0.f, a2 = 0.f, a3 = 0.f;
#pragma unroll
            for (int n = 0; n < NS_; ++n) {
                float4 u = ((const float4*)(emb + nid[row * NS_ + n] * D_))[dg];
                float al = alf[row * NS_ + n];
                a0 = fmaf(al, u.x, a0); a1 = fmaf(al, u.y, a1);
                a2 = fmaf(al, u.z, a2); a3 = fmaf(al, u.w, a3);
            }
            hwa[row][d4 + 0] = a0; hwa[row][d4 + 1] = a1;
            hwa[row][d4 + 2] = a2; hwa[row][d4 + 3] = a3;
        }
    }
    __syncthreads();

    // ---- hg = relu([h | agg] @ Wg); partial ssq ----
    float o[5][4] = {};
    if (act) {
        for (int k = 0; k < D_; ++k) {
            float4 w = ((const float4*)(Wg + k * D_))[dg];
#pragma unroll
            for (int i = 0; i < 5; ++i) {
                float xv = hL[sb + i][k];
                o[i][0] = fmaf(xv, w.x, o[i][0]); o[i][1] = fmaf(xv, w.y, o[i][1]);
                o[i][2] = fmaf(xv, w.z, o[i][2]); o[i][3] = fmaf(xv, w.w, o[i][3]);
            }
        }
        for (int k = 0; k < D_; ++k) {
            float4 w = ((const float4*)(Wg + (D_ + k) * D_))[dg];
#pragma unroll
            for (int i = 0; i < 5; ++i) {
                float xv = hwa[sb + i][k];   // agg
                o[i][0] = fmaf(xv, w.x, o[i][0]); o[i][1] = fmaf(xv, w.y, o[i][1]);
                o[i][2] = fmaf(xv, w.z, o[i][2]); o[i][3] = fmaf(xv, w.w, o[i][3]);
            }
        }
#pragma unroll
        for (int i = 0; i < 5; ++i) {
#pragma unroll
            for (int j = 0; j < 4; ++j) o[i][j] = fmaxf(o[i][j], 0.f);
            ssq[sb + i][dg] = o[i][0]*o[i][0] + o[i][1]*o[i][1]
                            + o[i][2]*o[i][2] + o[i][3]*o[i][3];
        }
    }
    __syncthreads();

    if (t < S_) {
        float ss = 0.f;
        for (int j = 0; j < 25; ++j) ss += ssq[t][j];
        rinv2[t] = s1 / fmaxf(sqrtf(ss), 1e-12f);
    }
    __syncthreads();

    // ---- combine + store fp32 ----
    if (act) {
#pragma unroll
        for (int i = 0; i < 5; ++i) {
            float f = rinv2[sb + i];
            int row = b * S_ + sb + i;
            float4 ov;
            ov.x = hl[i][0] + o[i][0] * f;
            ov.y = hl[i][1] + o[i][1] * f;
            ov.z = hl[i][2] + o[i][2] * f;
            ov.w = hl[i][3] + o[i][3] * f;
            ((float4*)(out + row * D_))[dg] = ov;
        }
    }
}

// ---------------------------------------------------------------------------
// Last-items attention branch -> last_hidden [B,D]. fp32.
// ---------------------------------------------------------------------------
__global__ __launch_bounds__(128) void last_kernel(
    const int* __restrict__ last_items,  // [B,LAST]
    const int* __restrict__ adj_items,   // [B,LAST*NADJ]
    const float* __restrict__ emb,
    const float* __restrict__ Wl,        // [D,D]
    float* __restrict__ out2)            // [B,D]
{
    __shared__ __align__(16) float ih[LAST_][D_];
    __shared__ __align__(16) float ah[LAST_][NADJ_][D_];
    __shared__ float qL[LAST_][D_];
    __shared__ float att[LAST_][NADJ_];
    __shared__ int li[LAST_];
    __shared__ int ai[LAST_ * NADJ_];

    const int b = blockIdx.x, t = threadIdx.x;

    if (t < LAST_) li[t] = last_items[b * LAST_ + t];
    if (t < LAST_ * NADJ_) ai[t] = adj_items[b * LAST_ * NADJ_ + t];
    __syncthreads();

    for (int e = t; e < LAST_ * D_ / 4; e += 128) {        // 75 quads
        int l = e / 25, dq = e - l * 25;
        ((float4*)&ih[0][0])[e] = ((const float4*)(emb + li[l] * D_))[dq];
    }
    for (int e = t; e < LAST_ * NADJ_ * D_ / 4; e += 128) { // 900 quads
        int j = e / 25, dq = e - j * 25;
        ((float4*)&ah[0][0][0])[e] = ((const float4*)(emb + ai[j] * D_))[dq];
    }
    __syncthreads();

    // q = item_h @ Wl (column reads, coalesced across lanes per k)
    for (int e = t; e < LAST_ * D_; e += 128) {
        int l = e / D_, d = e - l * D_;
        float a = 0.f;
        for (int k = 0; k < D_; ++k) a = fmaf(ih[l][k], Wl[k * D_ + d], a);
        qL[l][d] = a;
    }
    __syncthreads();

    if (t < LAST_ * NADJ_) {
        int l = t / NADJ_, n = t - l * NADJ_;
        float a = 0.f;
        for (int d = 0; d < D_; ++d) a = fmaf(qL[l][d], ah[l][n][d], a);
        att[l][n] = a * SCALE_;
    }
    __syncthreads();

    if (t < LAST_) {
        float mx = -1e30f;
        for (int n = 0; n < NADJ_; ++n) mx = fmaxf(mx, att[t][n]);
        float e[NADJ_]; float sm = 0.f;
        for (int n = 0; n < NADJ_; ++n) { e[n] = expf(att[t][n] - mx); sm += e[n]; }
        float inv = 1.f / sm;
        for (int n = 0; n < NADJ_; ++n) att[t][n] = e[n] * inv;
    }
    __syncthreads();

    if (t < D_) {
        float acc = 0.f;
        for (int l = 0; l < LAST_; ++l) {
            float a = ih[l][t];
            for (int n = 0; n < NADJ_; ++n) a = fmaf(att[l][n], ah[l][n][t], a);
            acc += a;
        }
        out2[b * D_ + t] = acc * (1.f / 3.f);
    }
}

// ---------------------------------------------------------------------------
extern "C" void kernel_launch(void* const* d_in, const int* in_sizes, int n_in,
                              void* d_out, int out_size, void* d_ws, size_t ws_size,
                              hipStream_t stream) {
    (void)in_sizes; (void)n_in; (void)out_size; (void)d_ws; (void)ws_size;
    const int* inputs     = (const int*)d_in[0];
    const float* adj      = (const float*)d_in[1];
    // d_in[2] = item (unused by reference)
    const int* last_items = (const int*)d_in[3];
    const int* adj_items  = (const int*)d_in[4];
    const float* emb      = (const float*)d_in[5];
    const float* sW       = (const float*)d_in[6];
    const float* Wa       = (const float*)d_in[7];
    const float* Wq       = (const float*)d_in[8];
    const float* Wk       = (const float*)d_in[9];
    const float* Wg       = (const float*)d_in[10];
    const float* Wl       = (const float*)d_in[11];
    const int* adj_all    = (const int*)d_in[12];
    const float* num_w    = (const float*)d_in[13];

    float* out = (float*)d_out;

    fused_kernel<<<B_, 256, 0, stream>>>(inputs, adj, emb, adj_all, num_w,
                                         sW, Wa, Wq, Wk, Wg, out);
    last_kernel<<<B_, 128, 0, stream>>>(last_items, adj_items, emb, Wl,
                                        out + B_ * S_ * D_);
}